// Round 5
// baseline (104.575 us; speedup 1.0000x reference)
//
#include <hip/hip_runtime.h>
#include <hip/hip_bf16.h>

#define BATCH 8
#define NPT   2048
#define DIM   512
#define NTILE 8             // 2048/256 tiles per dim
#define NTRI  36            // 8*9/2 symmetric tiles per batch
#define NBLK  (NTRI * BATCH) // 288

typedef __attribute__((ext_vector_type(8))) short bf16x8;
typedef __attribute__((ext_vector_type(4))) float f32x4;

// ---------------- workspace layout ----------------
#define OFF_SQ       16777216
#define OFF_MSUM     16842752
#define OFF_PARTIALS 16842784   // 288 floats

// ---------------- kernel 1: normalize rows, emit bf16 + per-row |x|^2 ----------------
__global__ __launch_bounds__(256) void normalize_kernel(const float* __restrict__ emb,
                                                        __hip_bfloat16* __restrict__ xn,
                                                        float* __restrict__ sq) {
    const int wave = threadIdx.x >> 6;
    const int lane = threadIdx.x & 63;
    const int row  = blockIdx.x * 4 + wave;

    const float4* src = (const float4*)(emb + (size_t)row * DIM);
    float4 v0 = src[lane * 2 + 0];
    float4 v1 = src[lane * 2 + 1];

    float ss = v0.x*v0.x + v0.y*v0.y + v0.z*v0.z + v0.w*v0.w
             + v1.x*v1.x + v1.y*v1.y + v1.z*v1.z + v1.w*v1.w;
#pragma unroll
    for (int o = 32; o; o >>= 1) ss += __shfl_xor(ss, o);

    const float inv = 1.0f / fmaxf(sqrtf(ss), 1e-12f);

    float vals[8] = {v0.x, v0.y, v0.z, v0.w, v1.x, v1.y, v1.z, v1.w};
    unsigned int w[4];
    float s2 = 0.f;
#pragma unroll
    for (int i = 0; i < 4; i++) {
        __hip_bfloat16 h0 = __float2bfloat16(vals[2*i]   * inv);
        __hip_bfloat16 h1 = __float2bfloat16(vals[2*i+1] * inv);
        unsigned short u0 = *(unsigned short*)&h0;
        unsigned short u1 = *(unsigned short*)&h1;
        w[i] = (unsigned int)u0 | ((unsigned int)u1 << 16);
        float f0 = __bfloat162float(h0), f1 = __bfloat162float(h1);
        s2 += f0*f0 + f1*f1;
    }
    uint4 pk = {w[0], w[1], w[2], w[3]};
    *(uint4*)(xn + (size_t)row * DIM + lane * 8) = pk;

#pragma unroll
    for (int o = 32; o; o >>= 1) s2 += __shfl_xor(s2, o);
    if (lane == 0) sq[row] = s2;
}

// ---------------- kernel 2: per-batch mask sums ----------------
__global__ __launch_bounds__(256) void masksum_kernel(const float* __restrict__ mask,
                                                      float* __restrict__ msum) {
    const int b = blockIdx.x;
    float s = 0.f;
    for (int i = threadIdx.x; i < NPT; i += 256) s += mask[b * NPT + i];
#pragma unroll
    for (int o = 32; o; o >>= 1) s += __shfl_xor(s, o);
    __shared__ float ws[4];
    if ((threadIdx.x & 63) == 0) ws[threadIdx.x >> 6] = s;
    __syncthreads();
    if (threadIdx.x == 0) msum[b] = ws[0] + ws[1] + ws[2] + ws[3];
}

// ---------------- kernel 3: 256x256 tiles, 16 k-slice phases (ROLLED), counted vmcnt ----------------
// 8 waves (2M x 4N), per-wave 128x64 output, mfma_f32_16x16x32_bf16.
// LDS: 4-region rotation per side (region = phase & 3), each region 256 rows x 32 k.
// Stage 3 phases ahead; vmcnt(8) steady state; 1 barrier/phase.
// ROLLED phase loop (unroll 1): round 2/3's 16x macro expansion made the compiler
// hoist ~13 staged address sets (~104 VGPR) -> ~236 B/thread scratch spills
// (WRITE_SIZE 34 MB, MfmaUtil 5.8%). Rolled loop keeps 2 base pointers + q*64B.
__global__ __launch_bounds__(512) void gram_loss_kernel(const __hip_bfloat16* __restrict__ xn,
                                                        const float* __restrict__ sq,
                                                        const float* __restrict__ coords,
                                                        const float* __restrict__ mask,
                                                        float* __restrict__ partials) {
    __shared__ __align__(16) __hip_bfloat16 ldsA[4][256 * 32];   // 64 KB
    __shared__ __align__(16) __hip_bfloat16 ldsB[4][256 * 32];   // 64 KB
    __shared__ float s_sqr[256], s_sqc[256], s_mr[256], s_mc[256];
    __shared__ float s_cr[256][3], s_cc[256][3];
    __shared__ float s_wsum[8];

    // XCD-chunked swizzle: 288 = 8 * 36, batch == XCD id -> per-XCD L2 panel locality
    const int bid = blockIdx.x;
    const int sw  = (bid & 7) * NTRI + (bid >> 3);
    const int b   = sw / NTRI;
    int r = sw % NTRI;
    int tm = 0;
    while (r >= NTILE - tm) { r -= NTILE - tm; tm++; }
    const int tn = tm + r;

    const int t    = threadIdx.x;
    const int wave = t >> 6, lane = t & 63;
    const int wr = wave >> 2, wc = wave & 3;      // 2 x 4 wave grid
    const int lhi = lane >> 4, llo = lane & 15;

    const size_t rowBaseA = (size_t)(b * NPT + tm * 256);
    const size_t rowBaseB = (size_t)(b * NPT + tn * 256);

    f32x4 acc[8][4];
#pragma unroll
    for (int i = 0; i < 8; i++)
#pragma unroll
        for (int j = 0; j < 4; j++) acc[i][j] = (f32x4){0.f, 0.f, 0.f, 0.f};

    // staging: region = 256 rows x 32 cols bf16 = 16 KB = 16 segments of 1 KB (16 rows).
    // wave w issues segments {2w, 2w+1} per side; lane l covers (row = seg*16 + (l>>2),
    // 64B slot l&3), source col pre-swizzled so stored slot = src_slot ^ ((row>>1)&3).
    // Region q's k-offset = q*32 elements -> base pointer + q*64 bytes.
    const int srow = lane >> 2;
    const int scol = ((lane & 3) ^ ((lane >> 3) & 3)) * 8;

    const int row0 = (wave * 2 + 0) * 16 + srow;
    const int row1 = (wave * 2 + 1) * 16 + srow;
    const __hip_bfloat16* gA0 = xn + (rowBaseA + row0) * DIM + scol;
    const __hip_bfloat16* gA1 = xn + (rowBaseA + row1) * DIM + scol;
    const __hip_bfloat16* gB0 = xn + (rowBaseB + row0) * DIM + scol;
    const __hip_bfloat16* gB1 = xn + (rowBaseB + row1) * DIM + scol;
    const int seg0 = (wave * 2 + 0) * 512;   // LDS elem offset of segment 2w
    const int seg1 = (wave * 2 + 1) * 512;

#define STAGE_REGION(q_)                                                                        \
    {                                                                                           \
        const int ko_ = (q_) * 32;                                                              \
        const int rg_ = (q_) & 3;                                                               \
        __builtin_amdgcn_global_load_lds((const __attribute__((address_space(1))) void*)(gA0 + ko_), \
            (__attribute__((address_space(3))) void*)(&ldsA[rg_][seg0]), 16, 0, 0);             \
        __builtin_amdgcn_global_load_lds((const __attribute__((address_space(1))) void*)(gA1 + ko_), \
            (__attribute__((address_space(3))) void*)(&ldsA[rg_][seg1]), 16, 0, 0);             \
        __builtin_amdgcn_global_load_lds((const __attribute__((address_space(1))) void*)(gB0 + ko_), \
            (__attribute__((address_space(3))) void*)(&ldsB[rg_][seg0]), 16, 0, 0);             \
        __builtin_amdgcn_global_load_lds((const __attribute__((address_space(1))) void*)(gB1 + ko_), \
            (__attribute__((address_space(3))) void*)(&ldsB[rg_][seg1]), 16, 0, 0);             \
    }

#define VMW(n_) asm volatile("s_waitcnt vmcnt(" #n_ ")" ::: "memory")

    // prologue: regions 0,1,2 in flight (12 loads/thread)
    STAGE_REGION(0);
    STAGE_REGION(1);
    STAGE_REGION(2);

    const int rsl = (lhi ^ ((llo >> 1) & 3)) * 16;   // swizzled 16B slot in 64B row

#define PHASE_BODY(p_)                                                                          \
    {                                                                                           \
        const char* baA = (const char*)ldsA[(p_) & 3];                                          \
        const char* baB = (const char*)ldsB[(p_) & 3];                                          \
        bf16x8 af[8], bfr[4];                                                                   \
        _Pragma("unroll")                                                                       \
        for (int mi = 0; mi < 8; mi++)                                                          \
            af[mi] = *(const bf16x8*)(baA + (wr * 128 + mi * 16 + llo) * 64 + rsl);             \
        _Pragma("unroll")                                                                       \
        for (int ni = 0; ni < 4; ni++)                                                          \
            bfr[ni] = *(const bf16x8*)(baB + (wc * 64 + ni * 16 + llo) * 64 + rsl);             \
        if ((p_) < 13) STAGE_REGION((p_) + 3);                                                  \
        __builtin_amdgcn_s_setprio(1);                                                          \
        _Pragma("unroll")                                                                       \
        for (int mi = 0; mi < 8; mi++)                                                          \
            _Pragma("unroll")                                                                   \
            for (int ni = 0; ni < 4; ni++)                                                      \
                acc[mi][ni] = __builtin_amdgcn_mfma_f32_16x16x32_bf16(af[mi], bfr[ni],          \
                                                                      acc[mi][ni], 0, 0, 0);    \
        __builtin_amdgcn_s_setprio(0);                                                          \
    }

#pragma unroll 1
    for (int p = 0; p < 14; p++) {
        VMW(8);                              // oldest 4 loads (region p) landed
        __builtin_amdgcn_s_barrier();
        PHASE_BODY(p);
    }
    VMW(4);
    __builtin_amdgcn_s_barrier();
    PHASE_BODY(14);
    VMW(0);
    __builtin_amdgcn_s_barrier();
    PHASE_BODY(15);

#undef PHASE_BODY
#undef STAGE_REGION
#undef VMW

    // stage per-row/col metadata for the epilogue
    if (t < 256) {
        const int gi = b * NPT + tm * 256 + t;
        s_sqr[t]   = sq[gi];
        s_mr[t]    = mask[gi];
        s_cr[t][0] = coords[(size_t)gi * 3 + 0];
        s_cr[t][1] = coords[(size_t)gi * 3 + 1];
        s_cr[t][2] = coords[(size_t)gi * 3 + 2];
    } else {
        const int rr = t - 256;
        const int gi = b * NPT + tn * 256 + rr;
        s_sqc[rr]   = sq[gi];
        s_mc[rr]    = mask[gi];
        s_cc[rr][0] = coords[(size_t)gi * 3 + 0];
        s_cc[rr][1] = coords[(size_t)gi * 3 + 1];
        s_cc[rr][2] = coords[(size_t)gi * 3 + 2];
    }
    __syncthreads();

    // C/D layout: col = lane&15, row = (lane>>4)*4 + reg
    float lsum = 0.f;
#pragma unroll
    for (int mi = 0; mi < 8; mi++) {
#pragma unroll
        for (int j = 0; j < 4; j++) {
            const int rl  = wr * 128 + mi * 16 + lhi * 4 + j;
            const float sqr = s_sqr[rl];
            const float mr  = s_mr[rl];
            const float cx = s_cr[rl][0], cy = s_cr[rl][1], cz = s_cr[rl][2];
#pragma unroll
            for (int ni = 0; ni < 4; ni++) {
                const int cl = wc * 64 + ni * 16 + llo;
                const float g  = acc[mi][ni][j];
                float d2 = sqr + s_sqc[cl] - 2.f * g;
                d2 = fmaxf(d2, 0.f);
                const float de = sqrtf(d2);
                const float lo = fmaxf(de - 1.0f, 0.f);
                const float dx = cx - s_cc[cl][0];
                const float dy = cy - s_cc[cl][1];
                const float dz = cz - s_cc[cl][2];
                const float cd2 = dx*dx + dy*dy + dz*dz;
                const float wgt = (cd2 < 100.0f) ? mr * s_mc[cl] : 0.f;
                lsum += lo * wgt;
            }
        }
    }
    // off-diagonal tiles stand for both (tm,tn) and (tn,tm)
    if (tm != tn) lsum *= 2.0f;

#pragma unroll
    for (int o = 32; o; o >>= 1) lsum += __shfl_xor(lsum, o);
    if (lane == 0) s_wsum[wave] = lsum;
    __syncthreads();
    if (t == 0) {
        float bs = 0.f;
#pragma unroll
        for (int i = 0; i < 8; i++) bs += s_wsum[i];
        partials[bid] = bs;
    }
}

// ---------------- kernel 4: final deterministic reduce ----------------
__global__ __launch_bounds__(256) void finalize_kernel(const float* __restrict__ partials,
                                                       const float* __restrict__ msum,
                                                       float* __restrict__ out) {
    double s = 0.0;
    for (int i = threadIdx.x; i < NBLK; i += 256) s += (double)partials[i];
#pragma unroll
    for (int o = 32; o; o >>= 1) s += __shfl_xor(s, o);
    __shared__ double ws[4];
    if ((threadIdx.x & 63) == 0) ws[threadIdx.x >> 6] = s;
    __syncthreads();
    if (threadIdx.x == 0) {
        const double tot = ws[0] + ws[1] + ws[2] + ws[3];
        double valid = 0.0;
        for (int bb = 0; bb < BATCH; bb++) valid += (double)msum[bb] * (double)msum[bb];
        out[0] = (float)(tot / (valid + 1e-8));
    }
}

extern "C" void kernel_launch(void* const* d_in, const int* in_sizes, int n_in,
                              void* d_out, int out_size, void* d_ws, size_t ws_size,
                              hipStream_t stream) {
    const float* emb    = (const float*)d_in[0];
    const float* coords = (const float*)d_in[1];
    const float* mask   = (const float*)d_in[2];

    char* ws = (char*)d_ws;
    __hip_bfloat16* xn = (__hip_bfloat16*)ws;
    float* sq          = (float*)(ws + OFF_SQ);
    float* msum        = (float*)(ws + OFF_MSUM);
    float* partials    = (float*)(ws + OFF_PARTIALS);
    float* out         = (float*)d_out;

    normalize_kernel<<<dim3(BATCH * NPT / 4), dim3(256), 0, stream>>>(emb, xn, sq);
    masksum_kernel<<<dim3(BATCH), dim3(256), 0, stream>>>(mask, msum);
    gram_loss_kernel<<<dim3(NBLK), dim3(512), 0, stream>>>(xn, sq, coords, mask, partials);
    finalize_kernel<<<dim3(1), dim3(256), 0, stream>>>(partials, msum, out);
}

// Round 6
// 70.689 us; speedup vs baseline: 1.4794x; 1.4794x over previous
//
#include <hip/hip_runtime.h>
#include <hip/hip_bf16.h>

#define BATCH 8
#define NPT   2048
#define DIM   512
#define NTILE 16            // 2048/128 tiles per dim
#define NTRI  136           // 16*17/2 symmetric tiles per batch
#define NBLK  (NTRI * BATCH) // 1088

typedef __attribute__((ext_vector_type(8))) short bf16x8;
typedef __attribute__((ext_vector_type(4))) float f32x4;

// ---------------- workspace layout ----------------
#define OFF_SQ       16777216
#define OFF_MSUM     16842752
#define OFF_PARTIALS 16842784   // 1088 floats

// ---------------- kernel 1: normalize rows, emit bf16 + per-row |x|^2 ----------------
__global__ __launch_bounds__(256) void normalize_kernel(const float* __restrict__ emb,
                                                        __hip_bfloat16* __restrict__ xn,
                                                        float* __restrict__ sq) {
    const int wave = threadIdx.x >> 6;
    const int lane = threadIdx.x & 63;
    const int row  = blockIdx.x * 4 + wave;

    const float4* src = (const float4*)(emb + (size_t)row * DIM);
    float4 v0 = src[lane * 2 + 0];
    float4 v1 = src[lane * 2 + 1];

    float ss = v0.x*v0.x + v0.y*v0.y + v0.z*v0.z + v0.w*v0.w
             + v1.x*v1.x + v1.y*v1.y + v1.z*v1.z + v1.w*v1.w;
#pragma unroll
    for (int o = 32; o; o >>= 1) ss += __shfl_xor(ss, o);

    const float inv = 1.0f / fmaxf(sqrtf(ss), 1e-12f);

    float vals[8] = {v0.x, v0.y, v0.z, v0.w, v1.x, v1.y, v1.z, v1.w};
    unsigned int w[4];
    float s2 = 0.f;
#pragma unroll
    for (int i = 0; i < 4; i++) {
        __hip_bfloat16 h0 = __float2bfloat16(vals[2*i]   * inv);
        __hip_bfloat16 h1 = __float2bfloat16(vals[2*i+1] * inv);
        unsigned short u0 = *(unsigned short*)&h0;
        unsigned short u1 = *(unsigned short*)&h1;
        w[i] = (unsigned int)u0 | ((unsigned int)u1 << 16);
        float f0 = __bfloat162float(h0), f1 = __bfloat162float(h1);
        s2 += f0*f0 + f1*f1;
    }
    uint4 pk = {w[0], w[1], w[2], w[3]};
    *(uint4*)(xn + (size_t)row * DIM + lane * 8) = pk;

#pragma unroll
    for (int o = 32; o; o >>= 1) s2 += __shfl_xor(s2, o);
    if (lane == 0) sq[row] = s2;
}

// ---------------- kernel 2: per-batch mask sums ----------------
__global__ __launch_bounds__(256) void masksum_kernel(const float* __restrict__ mask,
                                                      float* __restrict__ msum) {
    const int b = blockIdx.x;
    float s = 0.f;
    for (int i = threadIdx.x; i < NPT; i += 256) s += mask[b * NPT + i];
#pragma unroll
    for (int o = 32; o; o >>= 1) s += __shfl_xor(s, o);
    __shared__ float ws[4];
    if ((threadIdx.x & 63) == 0) ws[threadIdx.x >> 6] = s;
    __syncthreads();
    if (threadIdx.x == 0) msum[b] = ws[0] + ws[1] + ws[2] + ws[3];
}

// ---------------- kernel 3: 128x128 tiles, 16 k-phases, 4-region counted vmcnt ----------------
// 4 waves (2x2), per-wave 64x64 output -> acc[4][4] = 64 regs (fits: 2 blk/CU =
// 2 waves/SIMD = 256 unified regs/wave; round 2-4's 256^2 shape needed ~320 -> spilled).
// LDS 69 KB -> 2 blocks/CU. Region = 128 rows x 32 k per side; rotate (phase & 3);
// stage 3 ahead; vmcnt(8) steady state (4 loads/thread/region); 1 barrier/phase.
__global__ __launch_bounds__(256) void gram_loss_kernel(const __hip_bfloat16* __restrict__ xn,
                                                        const float* __restrict__ sq,
                                                        const float* __restrict__ coords,
                                                        const float* __restrict__ mask,
                                                        float* __restrict__ partials) {
    __shared__ __align__(16) __hip_bfloat16 ldsA[4][128 * 32];   // 32 KB
    __shared__ __align__(16) __hip_bfloat16 ldsB[4][128 * 32];   // 32 KB
    __shared__ float s_sqr[128], s_sqc[128], s_mr[128], s_mc[128];
    __shared__ float s_cr[128][3], s_cc[128][3];
    __shared__ float s_wsum[4];

    // XCD-chunked: 1088 = 8 * 136; batch == XCD id -> 2 MB panel set per XCD L2
    const int bid = blockIdx.x;
    const int b   = bid & 7;
    int r = bid >> 3;
    int tm = 0;
    while (r >= NTILE - tm) { r -= NTILE - tm; tm++; }
    const int tn = tm + r;

    const int t    = threadIdx.x;
    const int wave = t >> 6, lane = t & 63;
    const int wr = wave >> 1, wc = wave & 1;      // 2 x 2 wave grid
    const int lhi = lane >> 4, llo = lane & 15;

    const size_t rowBaseA = (size_t)(b * NPT + tm * 128);
    const size_t rowBaseB = (size_t)(b * NPT + tn * 128);

    f32x4 acc[4][4];
#pragma unroll
    for (int i = 0; i < 4; i++)
#pragma unroll
        for (int j = 0; j < 4; j++) acc[i][j] = (f32x4){0.f, 0.f, 0.f, 0.f};

    // staging: region = 128 rows x 32 cols bf16 = 8 KB = 8 segments of 1 KB (16 rows).
    // wave w issues segments {2w, 2w+1} per side; lane l covers (row = seg*16 + (l>>2),
    // 64B slot l&3); source col pre-swizzled so stored slot = src_slot ^ ((row>>1)&3).
    // Region q's k-offset = q*32 elements = q*64 bytes from base pointer.
    const int srow = lane >> 2;
    const int scol = ((lane & 3) ^ ((lane >> 3) & 3)) * 8;

    const int row0 = (wave * 2 + 0) * 16 + srow;
    const int row1 = (wave * 2 + 1) * 16 + srow;
    const __hip_bfloat16* gA0 = xn + (rowBaseA + row0) * DIM + scol;
    const __hip_bfloat16* gA1 = xn + (rowBaseA + row1) * DIM + scol;
    const __hip_bfloat16* gB0 = xn + (rowBaseB + row0) * DIM + scol;
    const __hip_bfloat16* gB1 = xn + (rowBaseB + row1) * DIM + scol;
    const int seg0 = (wave * 2 + 0) * 512;   // LDS elem offset of segment 2w
    const int seg1 = (wave * 2 + 1) * 512;

#define STAGE_REGION(q_)                                                                        \
    {                                                                                           \
        const int ko_ = (q_) * 32;                                                              \
        const int rg_ = (q_) & 3;                                                               \
        __builtin_amdgcn_global_load_lds((const __attribute__((address_space(1))) void*)(gA0 + ko_), \
            (__attribute__((address_space(3))) void*)(&ldsA[rg_][seg0]), 16, 0, 0);             \
        __builtin_amdgcn_global_load_lds((const __attribute__((address_space(1))) void*)(gA1 + ko_), \
            (__attribute__((address_space(3))) void*)(&ldsA[rg_][seg1]), 16, 0, 0);             \
        __builtin_amdgcn_global_load_lds((const __attribute__((address_space(1))) void*)(gB0 + ko_), \
            (__attribute__((address_space(3))) void*)(&ldsB[rg_][seg0]), 16, 0, 0);             \
        __builtin_amdgcn_global_load_lds((const __attribute__((address_space(1))) void*)(gB1 + ko_), \
            (__attribute__((address_space(3))) void*)(&ldsB[rg_][seg1]), 16, 0, 0);             \
    }

#define VMW(n_) asm volatile("s_waitcnt vmcnt(" #n_ ")" ::: "memory")

    // prologue: regions 0,1,2 in flight (12 loads/thread)
    STAGE_REGION(0);
    STAGE_REGION(1);
    STAGE_REGION(2);

    const int rsl = (lhi ^ ((llo >> 1) & 3)) * 16;   // swizzled 16B slot in 64B row

#define PHASE_BODY(p_)                                                                          \
    {                                                                                           \
        const char* baA = (const char*)ldsA[(p_) & 3];                                          \
        const char* baB = (const char*)ldsB[(p_) & 3];                                          \
        bf16x8 af[4], bfr[4];                                                                   \
        _Pragma("unroll")                                                                       \
        for (int mi = 0; mi < 4; mi++)                                                          \
            af[mi] = *(const bf16x8*)(baA + (wr * 64 + mi * 16 + llo) * 64 + rsl);              \
        _Pragma("unroll")                                                                       \
        for (int ni = 0; ni < 4; ni++)                                                          \
            bfr[ni] = *(const bf16x8*)(baB + (wc * 64 + ni * 16 + llo) * 64 + rsl);             \
        if ((p_) < 13) STAGE_REGION((p_) + 3);                                                  \
        __builtin_amdgcn_s_setprio(1);                                                          \
        _Pragma("unroll")                                                                       \
        for (int mi = 0; mi < 4; mi++)                                                          \
            _Pragma("unroll")                                                                   \
            for (int ni = 0; ni < 4; ni++)                                                      \
                acc[mi][ni] = __builtin_amdgcn_mfma_f32_16x16x32_bf16(af[mi], bfr[ni],          \
                                                                      acc[mi][ni], 0, 0, 0);    \
        __builtin_amdgcn_s_setprio(0);                                                          \
    }

#pragma unroll 1
    for (int p = 0; p < 14; p++) {
        VMW(8);                              // oldest 4 loads (region p) landed
        __builtin_amdgcn_s_barrier();
        PHASE_BODY(p);
    }
    VMW(4);
    __builtin_amdgcn_s_barrier();
    PHASE_BODY(14);
    VMW(0);
    __builtin_amdgcn_s_barrier();
    PHASE_BODY(15);

#undef PHASE_BODY
#undef STAGE_REGION
#undef VMW

    // stage per-row/col metadata for the epilogue
    if (t < 128) {
        const int gi = b * NPT + tm * 128 + t;
        s_sqr[t]   = sq[gi];
        s_mr[t]    = mask[gi];
        s_cr[t][0] = coords[(size_t)gi * 3 + 0];
        s_cr[t][1] = coords[(size_t)gi * 3 + 1];
        s_cr[t][2] = coords[(size_t)gi * 3 + 2];
    } else {
        const int rr = t - 128;
        const int gi = b * NPT + tn * 128 + rr;
        s_sqc[rr]   = sq[gi];
        s_mc[rr]    = mask[gi];
        s_cc[rr][0] = coords[(size_t)gi * 3 + 0];
        s_cc[rr][1] = coords[(size_t)gi * 3 + 1];
        s_cc[rr][2] = coords[(size_t)gi * 3 + 2];
    }
    __syncthreads();

    // C/D layout: col = lane&15, row = (lane>>4)*4 + reg
    float lsum = 0.f;
#pragma unroll
    for (int mi = 0; mi < 4; mi++) {
#pragma unroll
        for (int j = 0; j < 4; j++) {
            const int rl  = wr * 64 + mi * 16 + lhi * 4 + j;
            const float sqr = s_sqr[rl];
            const float mr  = s_mr[rl];
            const float cx = s_cr[rl][0], cy = s_cr[rl][1], cz = s_cr[rl][2];
#pragma unroll
            for (int ni = 0; ni < 4; ni++) {
                const int cl = wc * 64 + ni * 16 + llo;
                const float g  = acc[mi][ni][j];
                float d2 = sqr + s_sqc[cl] - 2.f * g;
                d2 = fmaxf(d2, 0.f);
                const float de = sqrtf(d2);
                const float lo = fmaxf(de - 1.0f, 0.f);
                const float dx = cx - s_cc[cl][0];
                const float dy = cy - s_cc[cl][1];
                const float dz = cz - s_cc[cl][2];
                const float cd2 = dx*dx + dy*dy + dz*dz;
                const float wgt = (cd2 < 100.0f) ? mr * s_mc[cl] : 0.f;
                lsum += lo * wgt;
            }
        }
    }
    // off-diagonal tiles stand for both (tm,tn) and (tn,tm)
    if (tm != tn) lsum *= 2.0f;

#pragma unroll
    for (int o = 32; o; o >>= 1) lsum += __shfl_xor(lsum, o);
    if (lane == 0) s_wsum[wave] = lsum;
    __syncthreads();
    if (t == 0) {
        partials[bid] = s_wsum[0] + s_wsum[1] + s_wsum[2] + s_wsum[3];
    }
}

// ---------------- kernel 4: final deterministic reduce ----------------
__global__ __launch_bounds__(256) void finalize_kernel(const float* __restrict__ partials,
                                                       const float* __restrict__ msum,
                                                       float* __restrict__ out) {
    double s = 0.0;
    for (int i = threadIdx.x; i < NBLK; i += 256) s += (double)partials[i];
#pragma unroll
    for (int o = 32; o; o >>= 1) s += __shfl_xor(s, o);
    __shared__ double ws[4];
    if ((threadIdx.x & 63) == 0) ws[threadIdx.x >> 6] = s;
    __syncthreads();
    if (threadIdx.x == 0) {
        const double tot = ws[0] + ws[1] + ws[2] + ws[3];
        double valid = 0.0;
        for (int bb = 0; bb < BATCH; bb++) valid += (double)msum[bb] * (double)msum[bb];
        out[0] = (float)(tot / (valid + 1e-8));
    }
}

extern "C" void kernel_launch(void* const* d_in, const int* in_sizes, int n_in,
                              void* d_out, int out_size, void* d_ws, size_t ws_size,
                              hipStream_t stream) {
    const float* emb    = (const float*)d_in[0];
    const float* coords = (const float*)d_in[1];
    const float* mask   = (const float*)d_in[2];

    char* ws = (char*)d_ws;
    __hip_bfloat16* xn = (__hip_bfloat16*)ws;
    float* sq          = (float*)(ws + OFF_SQ);
    float* msum        = (float*)(ws + OFF_MSUM);
    float* partials    = (float*)(ws + OFF_PARTIALS);
    float* out         = (float*)d_out;

    normalize_kernel<<<dim3(BATCH * NPT / 4), dim3(256), 0, stream>>>(emb, xn, sq);
    masksum_kernel<<<dim3(BATCH), dim3(256), 0, stream>>>(mask, msum);
    gram_loss_kernel<<<dim3(NBLK), dim3(256), 0, stream>>>(xn, sq, coords, mask, partials);
    finalize_kernel<<<dim3(1), dim3(256), 0, stream>>>(partials, msum, out);
}

// Round 7
// 70.339 us; speedup vs baseline: 1.4867x; 1.0050x over previous
//
#include <hip/hip_runtime.h>
#include <hip/hip_bf16.h>

#define BATCH 8
#define NPT   2048
#define DIM   512
#define NTILE 16            // 2048/128 tiles per dim
#define NTRI  136           // 16*17/2 symmetric tiles per batch
#define NBLK  (NTRI * BATCH) // 1088

typedef __attribute__((ext_vector_type(8))) short bf16x8;
typedef __attribute__((ext_vector_type(4))) float f32x4;

// ---------------- workspace layout ----------------
#define OFF_SQ       16777216
#define OFF_MSUM     16842752
#define OFF_PARTIALS 16842784   // 1088 floats

// ---------------- kernel 1: normalize rows, emit bf16 + per-row |x|^2 ----------------
__global__ __launch_bounds__(256) void normalize_kernel(const float* __restrict__ emb,
                                                        __hip_bfloat16* __restrict__ xn,
                                                        float* __restrict__ sq) {
    const int wave = threadIdx.x >> 6;
    const int lane = threadIdx.x & 63;
    const int row  = blockIdx.x * 4 + wave;

    const float4* src = (const float4*)(emb + (size_t)row * DIM);
    float4 v0 = src[lane * 2 + 0];
    float4 v1 = src[lane * 2 + 1];

    float ss = v0.x*v0.x + v0.y*v0.y + v0.z*v0.z + v0.w*v0.w
             + v1.x*v1.x + v1.y*v1.y + v1.z*v1.z + v1.w*v1.w;
#pragma unroll
    for (int o = 32; o; o >>= 1) ss += __shfl_xor(ss, o);

    const float inv = 1.0f / fmaxf(sqrtf(ss), 1e-12f);

    float vals[8] = {v0.x, v0.y, v0.z, v0.w, v1.x, v1.y, v1.z, v1.w};
    unsigned int w[4];
    float s2 = 0.f;
#pragma unroll
    for (int i = 0; i < 4; i++) {
        __hip_bfloat16 h0 = __float2bfloat16(vals[2*i]   * inv);
        __hip_bfloat16 h1 = __float2bfloat16(vals[2*i+1] * inv);
        unsigned short u0 = *(unsigned short*)&h0;
        unsigned short u1 = *(unsigned short*)&h1;
        w[i] = (unsigned int)u0 | ((unsigned int)u1 << 16);
        float f0 = __bfloat162float(h0), f1 = __bfloat162float(h1);
        s2 += f0*f0 + f1*f1;
    }
    uint4 pk = {w[0], w[1], w[2], w[3]};
    *(uint4*)(xn + (size_t)row * DIM + lane * 8) = pk;

#pragma unroll
    for (int o = 32; o; o >>= 1) s2 += __shfl_xor(s2, o);
    if (lane == 0) sq[row] = s2;
}

// ---------------- kernel 2: per-batch mask sums ----------------
__global__ __launch_bounds__(256) void masksum_kernel(const float* __restrict__ mask,
                                                      float* __restrict__ msum) {
    const int b = blockIdx.x;
    float s = 0.f;
    for (int i = threadIdx.x; i < NPT; i += 256) s += mask[b * NPT + i];
#pragma unroll
    for (int o = 32; o; o >>= 1) s += __shfl_xor(s, o);
    __shared__ float ws[4];
    if ((threadIdx.x & 63) == 0) ws[threadIdx.x >> 6] = s;
    __syncthreads();
    if (threadIdx.x == 0) msum[b] = ws[0] + ws[1] + ws[2] + ws[3];
}

// ---------------- kernel 3: 128x128 tiles, 16 k-phases, m201-style TWO-BARRIER phases ----------------
// 4 waves (2x2), per-wave 64x64, acc[4][4]=64 regs. 4-region rotation, BK=32.
// Phase: {ds_read(region p) | STAGE(p+3) | counted VMW | barrier | lgkmcnt(0)+sched_barrier
//         | setprio(1) 16xMFMA setprio(0) | barrier}.
// VMW schedule (4 loads/thread/region, 3 regions in flight): prologue stages r0..r2,
// VMW(8)+barrier confirms r0; phase p<=12 stages r(p+3) then VMW(8) confirms r(p+1)
// (2-phase flight time); p13 VMW(4) confirms r14; p14 VMW(0) confirms r15.
// Trailing barrier = write-after-read fence: STAGE(p+3) overwrites region (p-1)&3,
// whose reads were consumed before phase p-1's trailing barrier.
__global__ __launch_bounds__(256) void gram_loss_kernel(const __hip_bfloat16* __restrict__ xn,
                                                        const float* __restrict__ sq,
                                                        const float* __restrict__ coords,
                                                        const float* __restrict__ mask,
                                                        float* __restrict__ partials) {
    __shared__ __align__(16) __hip_bfloat16 ldsA[4][128 * 32];   // 32 KB
    __shared__ __align__(16) __hip_bfloat16 ldsB[4][128 * 32];   // 32 KB
    __shared__ float s_sqr[128], s_sqc[128], s_mr[128], s_mc[128];
    __shared__ float s_cr[128][3], s_cc[128][3];
    __shared__ float s_wsum[4];

    // XCD-chunked: 1088 = 8 * 136; batch == XCD id -> 2 MB panel set per XCD L2
    const int bid = blockIdx.x;
    const int b   = bid & 7;
    int r = bid >> 3;
    int tm = 0;
    while (r >= NTILE - tm) { r -= NTILE - tm; tm++; }
    const int tn = tm + r;

    const int t    = threadIdx.x;
    const int wave = t >> 6, lane = t & 63;
    const int wr = wave >> 1, wc = wave & 1;      // 2 x 2 wave grid
    const int lhi = lane >> 4, llo = lane & 15;

    const size_t rowBaseA = (size_t)(b * NPT + tm * 128);
    const size_t rowBaseB = (size_t)(b * NPT + tn * 128);

    f32x4 acc[4][4];
#pragma unroll
    for (int i = 0; i < 4; i++)
#pragma unroll
        for (int j = 0; j < 4; j++) acc[i][j] = (f32x4){0.f, 0.f, 0.f, 0.f};

    // staging: region = 128 rows x 32 cols bf16 = 8 KB/side = 8 segments of 1 KB (16 rows).
    // wave w issues segments {2w, 2w+1} per side; lane l covers (row = seg*16 + (l>>2),
    // 64B slot l&3); source col pre-swizzled so stored slot = src_slot ^ ((row>>1)&3).
    const int srow = lane >> 2;
    const int scol = ((lane & 3) ^ ((lane >> 3) & 3)) * 8;

    const int row0 = (wave * 2 + 0) * 16 + srow;
    const int row1 = (wave * 2 + 1) * 16 + srow;
    const __hip_bfloat16* gA0 = xn + (rowBaseA + row0) * DIM + scol;
    const __hip_bfloat16* gA1 = xn + (rowBaseA + row1) * DIM + scol;
    const __hip_bfloat16* gB0 = xn + (rowBaseB + row0) * DIM + scol;
    const __hip_bfloat16* gB1 = xn + (rowBaseB + row1) * DIM + scol;
    const int seg0 = (wave * 2 + 0) * 512;   // LDS elem offset of segment 2w
    const int seg1 = (wave * 2 + 1) * 512;

#define STAGE_REGION(q_)                                                                        \
    {                                                                                           \
        const int ko_ = (q_) * 32;                                                              \
        const int rg_ = (q_) & 3;                                                               \
        __builtin_amdgcn_global_load_lds((const __attribute__((address_space(1))) void*)(gA0 + ko_), \
            (__attribute__((address_space(3))) void*)(&ldsA[rg_][seg0]), 16, 0, 0);             \
        __builtin_amdgcn_global_load_lds((const __attribute__((address_space(1))) void*)(gA1 + ko_), \
            (__attribute__((address_space(3))) void*)(&ldsA[rg_][seg1]), 16, 0, 0);             \
        __builtin_amdgcn_global_load_lds((const __attribute__((address_space(1))) void*)(gB0 + ko_), \
            (__attribute__((address_space(3))) void*)(&ldsB[rg_][seg0]), 16, 0, 0);             \
        __builtin_amdgcn_global_load_lds((const __attribute__((address_space(1))) void*)(gB1 + ko_), \
            (__attribute__((address_space(3))) void*)(&ldsB[rg_][seg1]), 16, 0, 0);             \
    }

#define VMW(n_) asm volatile("s_waitcnt vmcnt(" #n_ ")" ::: "memory")

    // prologue: regions 0,1,2 in flight; confirm region 0 for phase 0
    STAGE_REGION(0);
    STAGE_REGION(1);
    STAGE_REGION(2);
    VMW(8);
    __builtin_amdgcn_s_barrier();

    const int rsl = (lhi ^ ((llo >> 1) & 3)) * 16;   // swizzled 16B slot in 64B row

#define PHASE_BODY(p_, vm_, dostage_)                                                           \
    {                                                                                           \
        const char* baA = (const char*)ldsA[(p_) & 3];                                          \
        const char* baB = (const char*)ldsB[(p_) & 3];                                          \
        bf16x8 af[4], bfr[4];                                                                   \
        _Pragma("unroll")                                                                       \
        for (int mi = 0; mi < 4; mi++)                                                          \
            af[mi] = *(const bf16x8*)(baA + (wr * 64 + mi * 16 + llo) * 64 + rsl);              \
        _Pragma("unroll")                                                                       \
        for (int ni = 0; ni < 4; ni++)                                                          \
            bfr[ni] = *(const bf16x8*)(baB + (wc * 64 + ni * 16 + llo) * 64 + rsl);             \
        if (dostage_) STAGE_REGION((p_) + 3);                                                   \
        VMW(vm_);                                                                               \
        __builtin_amdgcn_s_barrier();                                                           \
        asm volatile("s_waitcnt lgkmcnt(0)" ::: "memory");                                      \
        __builtin_amdgcn_sched_barrier(0);                                                      \
        __builtin_amdgcn_s_setprio(1);                                                          \
        _Pragma("unroll")                                                                       \
        for (int mi = 0; mi < 4; mi++)                                                          \
            _Pragma("unroll")                                                                   \
            for (int ni = 0; ni < 4; ni++)                                                      \
                acc[mi][ni] = __builtin_amdgcn_mfma_f32_16x16x32_bf16(af[mi], bfr[ni],          \
                                                                      acc[mi][ni], 0, 0, 0);    \
        __builtin_amdgcn_s_setprio(0);                                                          \
        __builtin_amdgcn_s_barrier();                                                           \
    }

#pragma unroll 1
    for (int p = 0; p < 13; p++) {
        PHASE_BODY(p, 8, 1);
    }
    PHASE_BODY(13, 4, 0);
    PHASE_BODY(14, 0, 0);
    PHASE_BODY(15, 0, 0);

#undef PHASE_BODY
#undef STAGE_REGION
#undef VMW

    // stage per-row/col metadata for the epilogue
    if (t < 128) {
        const int gi = b * NPT + tm * 128 + t;
        s_sqr[t]   = sq[gi];
        s_mr[t]    = mask[gi];
        s_cr[t][0] = coords[(size_t)gi * 3 + 0];
        s_cr[t][1] = coords[(size_t)gi * 3 + 1];
        s_cr[t][2] = coords[(size_t)gi * 3 + 2];
    } else {
        const int rr = t - 128;
        const int gi = b * NPT + tn * 128 + rr;
        s_sqc[rr]   = sq[gi];
        s_mc[rr]    = mask[gi];
        s_cc[rr][0] = coords[(size_t)gi * 3 + 0];
        s_cc[rr][1] = coords[(size_t)gi * 3 + 1];
        s_cc[rr][2] = coords[(size_t)gi * 3 + 2];
    }
    __syncthreads();

    // C/D layout: col = lane&15, row = (lane>>4)*4 + reg
    float lsum = 0.f;
#pragma unroll
    for (int mi = 0; mi < 4; mi++) {
#pragma unroll
        for (int j = 0; j < 4; j++) {
            const int rl  = wr * 64 + mi * 16 + lhi * 4 + j;
            const float sqr = s_sqr[rl];
            const float mr  = s_mr[rl];
            const float cx = s_cr[rl][0], cy = s_cr[rl][1], cz = s_cr[rl][2];
#pragma unroll
            for (int ni = 0; ni < 4; ni++) {
                const int cl = wc * 64 + ni * 16 + llo;
                const float g  = acc[mi][ni][j];
                float d2 = sqr + s_sqc[cl] - 2.f * g;
                d2 = fmaxf(d2, 0.f);
                const float de = sqrtf(d2);
                const float lo = fmaxf(de - 1.0f, 0.f);
                const float dx = cx - s_cc[cl][0];
                const float dy = cy - s_cc[cl][1];
                const float dz = cz - s_cc[cl][2];
                const float cd2 = dx*dx + dy*dy + dz*dz;
                const float wgt = (cd2 < 100.0f) ? mr * s_mc[cl] : 0.f;
                lsum += lo * wgt;
            }
        }
    }
    // off-diagonal tiles stand for both (tm,tn) and (tn,tm)
    if (tm != tn) lsum *= 2.0f;

#pragma unroll
    for (int o = 32; o; o >>= 1) lsum += __shfl_xor(lsum, o);
    if (lane == 0) s_wsum[wave] = lsum;
    __syncthreads();
    if (t == 0) {
        partials[bid] = s_wsum[0] + s_wsum[1] + s_wsum[2] + s_wsum[3];
    }
}

// ---------------- kernel 4: final deterministic reduce ----------------
__global__ __launch_bounds__(256) void finalize_kernel(const float* __restrict__ partials,
                                                       const float* __restrict__ msum,
                                                       float* __restrict__ out) {
    double s = 0.0;
    for (int i = threadIdx.x; i < NBLK; i += 256) s += (double)partials[i];
#pragma unroll
    for (int o = 32; o; o >>= 1) s += __shfl_xor(s, o);
    __shared__ double ws[4];
    if ((threadIdx.x & 63) == 0) ws[threadIdx.x >> 6] = s;
    __syncthreads();
    if (threadIdx.x == 0) {
        const double tot = ws[0] + ws[1] + ws[2] + ws[3];
        double valid = 0.0;
        for (int bb = 0; bb < BATCH; bb++) valid += (double)msum[bb] * (double)msum[bb];
        out[0] = (float)(tot / (valid + 1e-8));
    }
}

extern "C" void kernel_launch(void* const* d_in, const int* in_sizes, int n_in,
                              void* d_out, int out_size, void* d_ws, size_t ws_size,
                              hipStream_t stream) {
    const float* emb    = (const float*)d_in[0];
    const float* coords = (const float*)d_in[1];
    const float* mask   = (const float*)d_in[2];

    char* ws = (char*)d_ws;
    __hip_bfloat16* xn = (__hip_bfloat16*)ws;
    float* sq          = (float*)(ws + OFF_SQ);
    float* msum        = (float*)(ws + OFF_MSUM);
    float* partials    = (float*)(ws + OFF_PARTIALS);
    float* out         = (float*)d_out;

    normalize_kernel<<<dim3(BATCH * NPT / 4), dim3(256), 0, stream>>>(emb, xn, sq);
    masksum_kernel<<<dim3(BATCH), dim3(256), 0, stream>>>(mask, msum);
    gram_loss_kernel<<<dim3(NBLK), dim3(256), 0, stream>>>(xn, sq, coords, mask, partials);
    finalize_kernel<<<dim3(1), dim3(256), 0, stream>>>(partials, msum, out);
}